// Round 12
// baseline (211.749 us; speedup 1.0000x reference)
//
#include <hip/hip_runtime.h>
#include <hip/hip_bf16.h>
#include <stdint.h>

// Problem constants (B=2, N=M=2048, C=1024, H=16, hd=64)
#define SEQ   2048
#define CH    1024
#define NH    16
#define HD    64

typedef short bf8 __attribute__((ext_vector_type(8)));   // 8 bf16 (4 VGPRs)
typedef short bf4 __attribute__((ext_vector_type(4)));   // 4 bf16 (2 VGPRs)
typedef float f4  __attribute__((ext_vector_type(4)));   // MFMA C/D frag
typedef unsigned short u16;

#define GAS(p) ((const __attribute__((address_space(1))) void*)(p))
#define LAS(p) ((__attribute__((address_space(3))) void*)(p))

__device__ __forceinline__ u16 f2bf(float f) {
  uint32_t u = __float_as_uint(f);
  u += 0x7fffu + ((u >> 16) & 1u);   // RNE
  return (u16)(u >> 16);
}

// packed f32x2 -> bf16x2 — PROVEN header path (rounds 4/5/7/8/10/11 passed).
// NOTE: hand-written v_cvt_pk_bf16_f32 asm broke correctness in round 6.
__device__ __forceinline__ uint32_t pk2bf(float a, float b) {
  float2 f; f.x = a; f.y = b;
  __hip_bfloat162 h = __float22bfloat162_rn(f);
  union { __hip_bfloat162 h; uint32_t u; } cv; cv.h = h;
  return cv.u;
}

// raw v_exp_f32 via builtin: scores bounded, libm guard not needed (r7 WIN)
__device__ __forceinline__ float fexp2(float x) {
#if __has_builtin(__builtin_amdgcn_exp2f)
  return __builtin_amdgcn_exp2f(x);
#else
  return exp2f(x);
#endif
}

__device__ __forceinline__ f4 MFMA32(bf8 a, bf8 b, f4 c) {
  return __builtin_amdgcn_mfma_f32_16x16x32_bf16(a, b, c, 0, 0, 0);
}

// K=16 MFMA: A-layout [m=l16][k=q*4+reg] == C/D layout of a 16x16 frag.
// r9 probe proved K=16 is NOT slower per-op than K=32; keep MFMA16.
__device__ __forceinline__ f4 MFMA16(bf4 a, bf4 b, f4 c) {
#if __has_builtin(__builtin_amdgcn_mfma_f32_16x16x16_bf16)
  return __builtin_amdgcn_mfma_f32_16x16x16_bf16(a, b, c, 0, 0, 0);
#elif __has_builtin(__builtin_amdgcn_mfma_f32_16x16x16bf16_1k)
  return __builtin_amdgcn_mfma_f32_16x16x16bf16_1k(a, b, c, 0, 0, 0);
#else
  f4 d = c;
  asm volatile("v_mfma_f32_16x16x16_bf16 %0, %1, %2, %0"
               : "+v"(d) : "v"(a), "v"(b));
  return d;
#endif
}

// -------- prep: fp32->bf16 activations + transpose-convert all weights ------
// grid.x: [0,8192) cvt (4 f32/thread) | [8192,12288) 32x32 transpose tiles
__global__ void prep(const float* __restrict__ ref, u16* __restrict__ refb,
                     const float* __restrict__ tgt, u16* __restrict__ tgtb,
                     const float* __restrict__ Wq, u16* __restrict__ Wqt,
                     const float* __restrict__ Wkv, u16* __restrict__ Wkvt,
                     const float* __restrict__ Wp, u16* __restrict__ Wpt) {
  __shared__ float tile[32][33];
  int blk = blockIdx.x;
  int t = threadIdx.x;
  if (blk < 8192) {
    const float* in; u16* out;
    if (blk < 4096) { in = ref; out = refb; } else { in = tgt; out = tgtb; blk -= 4096; }
    int i = (blk * 256 + t) * 4;
    float4 f = *reinterpret_cast<const float4*>(in + i);
    ushort4 o;
    o.x = f2bf(f.x); o.y = f2bf(f.y); o.z = f2bf(f.z); o.w = f2bf(f.w);
    *reinterpret_cast<ushort4*>(out + i) = o;
    return;
  }
  blk -= 8192;                       // 0..4095: x = blk & 127, y = blk >> 7
  int x = blk & 127, by = blk >> 7;
  const float* in; u16* out; int N;
  if (x < 32)       { in = Wq;  out = Wqt;  N = CH;     }
  else if (x < 96)  { in = Wkv; out = Wkvt; N = 2 * CH; x -= 32; }
  else              { in = Wp;  out = Wpt;  N = CH;     x -= 96; }
  const int K = CH;
  int bn = x * 32, bk = by * 32;
  int tx = t & 31, ty = t >> 5;
  #pragma unroll
  for (int i = ty; i < 32; i += 8)
    tile[i][tx] = in[(size_t)(bk + i) * N + bn + tx];
  __syncthreads();
  #pragma unroll
  for (int i = ty; i < 32; i += 8)
    out[(size_t)(bn + i) * K + bk + tx] = f2bf(tile[tx][i]);
}

// ---------------- fused Q-proj + KV-proj GEMM, dbuf, 3 blocks/CU -------------
// Block roles by blockIdx.x:
//   x <  8 : K  — TRANSPOSED operands (A=Wkvt rows [0,1024), B=refb rows)
//   8<=x<16: V  — native (A=refb rows, B=Wkvt rows [1024,2048)) — unchanged
//   x >= 16: Q  — TRANSPOSED (A=Wqt rows, B=tgtb rows), prescaled
// Transposed blocks put the CHANNEL dim on the C-row axis -> each lane holds
// 4 consecutive channels -> ushort4 stores (16/thread) instead of 64 scalar
// 2B scatter stores. K-loop body is identical (inputs are symmetric [row][k]).
__global__ __launch_bounds__(256, 3)
void gemm_qkv(const u16* __restrict__ tgtb, const u16* __restrict__ refb,
              const u16* __restrict__ Wqt, const u16* __restrict__ Wkvt,
              u16* __restrict__ qb, u16* __restrict__ karr, u16* __restrict__ varr)
{
  __shared__ __align__(16) u16 As[2][4096];
  __shared__ __align__(16) u16 Bs[2][4096];
  const int tid = threadIdx.x;
  const int lane = tid & 63, wave = tid >> 6;
  const int l16 = lane & 15, q = lane >> 4;
  const int x = blockIdx.x;
  const bool isQ = x >= 16;
  const bool isV = (!isQ) && (x >= 8);
  // A-role rows (staged to As, a-frags, C-row dim, i/wm) and
  // B-role rows (staged to Bs, b-frags, C-col dim, j/wn)
  const u16* Aptr; const u16* Bptr; int a0, b0;
  if (isV)      { Aptr = refb; Bptr = Wkvt; a0 = blockIdx.y * 128; b0 = x * 128; }
  else if (isQ) { Aptr = Wqt;  Bptr = tgtb; a0 = (x - 16) * 128;   b0 = blockIdx.y * 128; }
  else          { Aptr = Wkvt; Bptr = refb; a0 = x * 128;          b0 = blockIdx.y * 128; }
  const int wm = (wave >> 1) * 64, wn = (wave & 1) * 64;
  const int Kdim = CH;
  const int c = tid, c2 = tid + 256;
  const int ar = c >> 2, ac = (c & 3) << 3, ar2 = c2 >> 2, ac2 = (c2 & 3) << 3;

  f4 acc[4][4] = {};

  #define STAGE_G(buf, k0)                                                      \
    { __builtin_amdgcn_global_load_lds(                                         \
          GAS(&Aptr[(size_t)(a0 + ar) * Kdim + (k0) + ac]),                     \
          LAS(&As[buf][c << 3]), 16, 0, 0);                                     \
      __builtin_amdgcn_global_load_lds(                                         \
          GAS(&Aptr[(size_t)(a0 + ar2) * Kdim + (k0) + ac2]),                   \
          LAS(&As[buf][c2 << 3]), 16, 0, 0);                                    \
      __builtin_amdgcn_global_load_lds(                                         \
          GAS(&Bptr[(size_t)(b0 + ar) * Kdim + (k0) + ac]),                     \
          LAS(&Bs[buf][c << 3]), 16, 0, 0);                                     \
      __builtin_amdgcn_global_load_lds(                                         \
          GAS(&Bptr[(size_t)(b0 + ar2) * Kdim + (k0) + ac2]),                   \
          LAS(&Bs[buf][c2 << 3]), 16, 0, 0); }

  STAGE_G(0, 0);
  for (int kk = 0; kk < 32; ++kk) {
    __syncthreads();
    if (kk < 31) STAGE_G((kk + 1) & 1, (kk + 1) * 32);
    const u16* as = As[kk & 1];
    const u16* bs = Bs[kk & 1];
    bf8 a[4], b[4];
    #pragma unroll
    for (int i = 0; i < 4; ++i)
      a[i] = *reinterpret_cast<const bf8*>(&as[(wm + i * 16 + l16) * 32 + q * 8]);
    #pragma unroll
    for (int j = 0; j < 4; ++j)
      b[j] = *reinterpret_cast<const bf8*>(&bs[(wn + j * 16 + l16) * 32 + q * 8]);
    #pragma unroll
    for (int i = 0; i < 4; ++i)
      #pragma unroll
      for (int j = 0; j < 4; ++j)
        acc[i][j] = MFMA32(a[i], b[j], acc[i][j]);
  }
  #undef STAGE_G

  // epilogue — C/D layout: col = lane&15, row = (lane>>4)*4 + reg   [m89/m91]
  if (isV) {
    // native V path — verbatim from the proven kernel
    #pragma unroll
    for (int i = 0; i < 4; ++i) {
      const int mbase = a0 + wm + i * 16 + q * 4;
      const int b = mbase >> 11, ns0 = mbase & (SEQ - 1);
      #pragma unroll
      for (int j = 0; j < 4; ++j) {
        const int n = b0 + wn + j * 16 + l16;
        int c2v = n - CH, h = c2v >> 6, d = c2v & 63;
        size_t base = (size_t)(b * NH + h) * SEQ * HD;
        int off = (((ns0 >> 4) * 2 + (d >> 5)) * 4 + ((ns0 >> 2) & 3)) * 128
                  + (d & 15) * 8 + ((d >> 4) & 1) * 4;
        ushort4 st;
        st.x = f2bf(acc[i][j][0]); st.y = f2bf(acc[i][j][1]);
        st.z = f2bf(acc[i][j][2]); st.w = f2bf(acc[i][j][3]);
        *reinterpret_cast<ushort4*>(&varr[base + off]) = st;
      }
    }
  } else {
    // transposed K/Q path: C-row = channel nW (4 consecutive per lane),
    // C-col = activation row mA. ushort4 per (i,j).
    #pragma unroll
    for (int i = 0; i < 4; ++i) {
      const int nW0 = a0 + wm + i * 16 + q * 4;   // channel base, %4==0
      const int h = nW0 >> 6, d0 = nW0 & 63;      // d0..d0+3 within one head
      #pragma unroll
      for (int j = 0; j < 4; ++j) {
        const int mA = b0 + wn + j * 16 + l16;    // activation row
        const int b = mA >> 11, mm = mA & (SEQ - 1);
        if (isQ) {
          ushort4 st;
          st.x = f2bf(acc[i][j][0] * 0.1803368801f);
          st.y = f2bf(acc[i][j][1] * 0.1803368801f);
          st.z = f2bf(acc[i][j][2] * 0.1803368801f);
          st.w = f2bf(acc[i][j][3] * 0.1803368801f);
          *reinterpret_cast<ushort4*>(
              &qb[(size_t)((b * NH + h) * SEQ + mm) * HD + d0]) = st;
        } else {
          // unified karr addr(ns,d) = base + (((ns>>4)*2+(d>>5))*4
          //   + ((d>>3)&3))*128 + (d&7) + (ns&15)*8 ; r varies d (consecutive)
          size_t base = (size_t)(b * NH + h) * SEQ * HD;
          int off = (((mm >> 4) * 2 + (d0 >> 5)) * 4 + ((d0 >> 3) & 3)) * 128
                    + (d0 & 7) + (mm & 15) * 8;
          ushort4 st;
          st.x = f2bf(acc[i][j][0]); st.y = f2bf(acc[i][j][1]);
          st.z = f2bf(acc[i][j][2]); st.w = f2bf(acc[i][j][3]);
          *reinterpret_cast<ushort4*>(&karr[base + off]) = st;
        }
      }
    }
  }
}

// ------- out-proj GEMM: 64x128 tile, grid (8,64)=512 blocks -> 2/CU ---------
__global__ __launch_bounds__(256, 2)
void gemm_proj(const u16* __restrict__ A, const u16* __restrict__ Bt,
               float* __restrict__ fo, const float* __restrict__ bias)
{
  __shared__ __align__(16) u16 As[2][2048];   // 64 x 32
  __shared__ __align__(16) u16 Bs[2][4096];   // 128 x 32
  const int tid = threadIdx.x;
  const int lane = tid & 63, wave = tid >> 6;
  const int l16 = lane & 15, q = lane >> 4;
  const int m0 = blockIdx.y * 64, n0 = blockIdx.x * 128;
  const int wm = (wave >> 1) * 32, wn = (wave & 1) * 64;
  const int Kdim = CH;
  const int c = tid, c2 = tid + 256;
  const int ar = c >> 2, ac = (c & 3) << 3, ar2 = c2 >> 2, ac2 = (c2 & 3) << 3;

  f4 acc[2][4] = {};

  const int aar = c >> 2;            // 0..63
  const int aac = (c & 3) << 3;
  #define STAGE_P(buf, k0)                                                      \
    { __builtin_amdgcn_global_load_lds(                                         \
          GAS(&A[(size_t)(m0 + aar) * Kdim + (k0) + aac]),                      \
          LAS(&As[buf][c << 3]), 16, 0, 0);                                     \
      __builtin_amdgcn_global_load_lds(                                         \
          GAS(&Bt[(size_t)(n0 + ar) * Kdim + (k0) + ac]),                       \
          LAS(&Bs[buf][c << 3]), 16, 0, 0);                                     \
      __builtin_amdgcn_global_load_lds(                                         \
          GAS(&Bt[(size_t)(n0 + ar2) * Kdim + (k0) + ac2]),                     \
          LAS(&Bs[buf][c2 << 3]), 16, 0, 0); }

  STAGE_P(0, 0);
  for (int kk = 0; kk < 32; ++kk) {
    __syncthreads();
    if (kk < 31) STAGE_P((kk + 1) & 1, (kk + 1) * 32);
    const u16* as = As[kk & 1];
    const u16* bs = Bs[kk & 1];
    bf8 a[2], b[4];
    #pragma unroll
    for (int i = 0; i < 2; ++i)
      a[i] = *reinterpret_cast<const bf8*>(&as[(wm + i * 16 + l16) * 32 + q * 8]);
    #pragma unroll
    for (int j = 0; j < 4; ++j)
      b[j] = *reinterpret_cast<const bf8*>(&bs[(wn + j * 16 + l16) * 32 + q * 8]);
    #pragma unroll
    for (int i = 0; i < 2; ++i)
      #pragma unroll
      for (int j = 0; j < 4; ++j)
        acc[i][j] = MFMA32(a[i], b[j], acc[i][j]);
  }
  #undef STAGE_P

  #pragma unroll
  for (int i = 0; i < 2; ++i) {
    const int mbase = m0 + wm + i * 16 + q * 4;
    #pragma unroll
    for (int j = 0; j < 4; ++j) {
      const int n = n0 + wn + j * 16 + l16;
      #pragma unroll
      for (int r = 0; r < 4; ++r)
        fo[(size_t)(mbase + r) * CH + n] = acc[i][j][r] + bias[n];
    }
  }
}

// ------------- flash attention (transposed-S, fixed-max, NO split) ----------
// grid: (M/64, B*H), 256 threads (4 waves); wave owns 16 Q-rows. Full seq
// per block (KVBLK=64, 32 t-iters, LDS 32 KB). 1024 blocks -> 4/CU ->
// 16 waves/CU. Verbatim from round 11 (passed, 57.7 us).
__global__ __launch_bounds__(256, 4)
void attn(const u16* __restrict__ Q, const u16* __restrict__ Karr,
          const u16* __restrict__ Varr, u16* __restrict__ X)
{
  __shared__ __align__(16) u16 Ks[2][4096];   // 2 x 8 KB (64 x 64 tile)
  __shared__ __align__(16) u16 Vs[2][4096];   // 2 x 8 KB
  const int tid = threadIdx.x;
  const int lane = tid & 63;
  const int l16 = lane & 15, q = lane >> 4;
  const int bh = blockIdx.y;
  const int m0 = blockIdx.x * 64;
  const int wm = (tid >> 6) * 16;             // wave -> 16 Q-rows

  const u16* Qb = Q    + (size_t)bh * SEQ * HD;
  const u16* Kb = Karr + (size_t)bh * SEQ * HD;
  const u16* Vb = Varr + (size_t)bh * SEQ * HD;

  // Q fragments (b-operand layout [n=l16][k=q*8+j]), resident all kernel
  bf8 qf[2];
  #pragma unroll
  for (int s = 0; s < 2; ++s)
    qf[s] = *reinterpret_cast<const bf8*>(
        &Qb[(size_t)(m0 + wm + l16) * HD + s * 32 + q * 8]);

  const short one_bf = 0x3F80;               // bf16(1.0)
  const bf4 ones = {one_bf, one_bf, one_bf, one_bf};

  f4 o[4] = {};     // O frag: row m=q*4+r, col d=dt*16+l16
  f4 ds = {};       // denominator frag: ds[r] = rowsum for m=q*4+r

  // staging: tile = 64 rows x 64 dims = 4096 u16 per array; 256 thr x 16 elems
  #define STAGE_A(buf, t)                                                      \
    { __builtin_amdgcn_global_load_lds(GAS(Kb + (size_t)(t) * 4096 + tid * 8), \
                                       LAS(&Ks[buf][tid * 8]), 16, 0, 0);      \
      __builtin_amdgcn_global_load_lds(GAS(Kb + (size_t)(t) * 4096 + 2048 + tid * 8), \
                                       LAS(&Ks[buf][2048 + tid * 8]), 16, 0, 0); \
      __builtin_amdgcn_global_load_lds(GAS(Vb + (size_t)(t) * 4096 + tid * 8), \
                                       LAS(&Vs[buf][tid * 8]), 16, 0, 0);      \
      __builtin_amdgcn_global_load_lds(GAS(Vb + (size_t)(t) * 4096 + 2048 + tid * 8), \
                                       LAS(&Vs[buf][2048 + tid * 8]), 16, 0, 0); }

  STAGE_A(0, 0);
  for (int t = 0; t < 32; ++t) {
    __syncthreads();
    if (t < 31) STAGE_A((t + 1) & 1, t + 1);
    const u16* ks = Ks[t & 1];
    const u16* vs = Vs[t & 1];

    // S^T tiles + exp + pack, all in registers (4 x 16 k-rows per step)
    bf4 pa[4];
    #pragma unroll
    for (int j = 0; j < 4; ++j) {
      bf8 kf0 = *reinterpret_cast<const bf8*>(&ks[((j * 2 + 0) * 4 + q) * 128 + l16 * 8]);
      bf8 kf1 = *reinterpret_cast<const bf8*>(&ks[((j * 2 + 1) * 4 + q) * 128 + l16 * 8]);
      f4 zf = {};
      zf = MFMA32(kf0, qf[0], zf);
      zf = MFMA32(kf1, qf[1], zf);
      union { bf4 v; uint32_t u[2]; } w;
      w.u[0] = pk2bf(fexp2(zf[0]), fexp2(zf[1]));
      w.u[1] = pk2bf(fexp2(zf[2]), fexp2(zf[3]));
      pa[j] = w.v;
    }

    // O += P * V ; denominator += P * ones; V frags as b128 pairs
    #pragma unroll
    for (int j = 0; j < 4; ++j) {
      ds = MFMA16(pa[j], ones, ds);
      #pragma unroll
      for (int dh = 0; dh < 2; ++dh) {
        bf8 vv = *reinterpret_cast<const bf8*>(&vs[((j * 2 + dh) * 4 + q) * 128 + l16 * 8]);
        bf4 v0 = __builtin_shufflevector(vv, vv, 0, 1, 2, 3);
        bf4 v1 = __builtin_shufflevector(vv, vv, 4, 5, 6, 7);
        o[dh * 2 + 0] = MFMA16(pa[j], v0, o[dh * 2 + 0]);
        o[dh * 2 + 1] = MFMA16(pa[j], v1, o[dh * 2 + 1]);
      }
    }
  }
  #undef STAGE_A

  // normalize + write x[b, m, h*64+d] (bf16) directly
  const int b = bh >> 4, h = bh & (NH - 1);
  #pragma unroll
  for (int r = 0; r < 4; ++r) {
    float ir = 1.0f / ds[r];
    int m = m0 + wm + q * 4 + r;
    #pragma unroll
    for (int dt = 0; dt < 4; ++dt) {
      int d = dt * 16 + l16;
      X[(size_t)(b * SEQ + m) * CH + h * HD + d] = f2bf(o[dt][r] * ir);
    }
  }
}

// ---------------- launch ----------------
extern "C" void kernel_launch(void* const* d_in, const int* in_sizes, int n_in,
                              void* d_out, int out_size, void* d_ws, size_t ws_size,
                              hipStream_t stream) {
  const float* ref   = (const float*)d_in[0];   // [B,N,C]
  const float* tgt   = (const float*)d_in[1];   // [B,M,C]
  const float* Wq    = (const float*)d_in[2];   // [C,C]
  const float* Wkv   = (const float*)d_in[3];   // [C,2C]
  const float* Wproj = (const float*)d_in[4];   // [C,C]
  const float* bproj = (const float*)d_in[5];   // [C]
  float* out = (float*)d_out;                   // [B,M,C] fp32

  // workspace layout (bytes): total 56 MiB
  char* ws = (char*)d_ws;
  u16* refb = (u16*)(ws);                 // 8 MiB
  u16* tgtb = (u16*)(ws + (8  << 20));    // 8 MiB
  u16* Wqt  = (u16*)(ws + (16 << 20));    // 2 MiB  [C,C]^T
  u16* Wkvt = (u16*)(ws + (18 << 20));    // 4 MiB  [2C,C]^T
  u16* Wpt  = (u16*)(ws + (22 << 20));    // 2 MiB
  u16* qb   = (u16*)(ws + (24 << 20));    // 8 MiB  [B,H,M,hd] (pre-scaled)
  u16* karr = (u16*)(ws + (32 << 20));    // 8 MiB  a-frag order
  u16* varr = (u16*)(ws + (40 << 20));    // 8 MiB  paired b-frag order
  u16* xb   = (u16*)(ws + (48 << 20));    // 8 MiB  [B*M, C]

  prep<<<12288, 256, 0, stream>>>(ref, refb, tgt, tgtb, Wq, Wqt, Wkv, Wkvt, Wproj, Wpt);

  gemm_qkv<<<dim3(24, 32), 256, 0, stream>>>(tgtb, refb, Wqt, Wkvt, qb, karr, varr);

  attn<<<dim3(32, 32), 256, 0, stream>>>(qb, karr, varr, xb);

  gemm_proj<<<dim3(8, 64), 256, 0, stream>>>(xb, Wpt, out, bproj);
}

// Round 13
// 202.120 us; speedup vs baseline: 1.0476x; 1.0476x over previous
//
#include <hip/hip_runtime.h>
#include <hip/hip_bf16.h>
#include <stdint.h>

// Problem constants (B=2, N=M=2048, C=1024, H=16, hd=64)
#define SEQ   2048
#define CH    1024
#define NH    16
#define HD    64

typedef short bf8 __attribute__((ext_vector_type(8)));   // 8 bf16 (4 VGPRs)
typedef short bf4 __attribute__((ext_vector_type(4)));   // 4 bf16 (2 VGPRs)
typedef float f4  __attribute__((ext_vector_type(4)));   // MFMA C/D frag
typedef unsigned short u16;

#define GAS(p) ((const __attribute__((address_space(1))) void*)(p))
#define LAS(p) ((__attribute__((address_space(3))) void*)(p))

__device__ __forceinline__ u16 f2bf(float f) {
  uint32_t u = __float_as_uint(f);
  u += 0x7fffu + ((u >> 16) & 1u);   // RNE
  return (u16)(u >> 16);
}

// packed f32x2 -> bf16x2 — PROVEN header path (rounds 4/5/7/8/10/11 passed).
// NOTE: hand-written v_cvt_pk_bf16_f32 asm broke correctness in round 6.
__device__ __forceinline__ uint32_t pk2bf(float a, float b) {
  float2 f; f.x = a; f.y = b;
  __hip_bfloat162 h = __float22bfloat162_rn(f);
  union { __hip_bfloat162 h; uint32_t u; } cv; cv.h = h;
  return cv.u;
}

// raw v_exp_f32 via builtin: scores bounded, libm guard not needed (r7 WIN)
__device__ __forceinline__ float fexp2(float x) {
#if __has_builtin(__builtin_amdgcn_exp2f)
  return __builtin_amdgcn_exp2f(x);
#else
  return exp2f(x);
#endif
}

__device__ __forceinline__ f4 MFMA32(bf8 a, bf8 b, f4 c) {
  return __builtin_amdgcn_mfma_f32_16x16x32_bf16(a, b, c, 0, 0, 0);
}

// K=16 MFMA: A-layout [m=l16][k=q*4+reg] == C/D layout of a 16x16 frag.
// r9 probe proved K=16 is NOT slower per-op than K=32; keep MFMA16.
__device__ __forceinline__ f4 MFMA16(bf4 a, bf4 b, f4 c) {
#if __has_builtin(__builtin_amdgcn_mfma_f32_16x16x16_bf16)
  return __builtin_amdgcn_mfma_f32_16x16x16_bf16(a, b, c, 0, 0, 0);
#elif __has_builtin(__builtin_amdgcn_mfma_f32_16x16x16bf16_1k)
  return __builtin_amdgcn_mfma_f32_16x16x16bf16_1k(a, b, c, 0, 0, 0);
#else
  f4 d = c;
  asm volatile("v_mfma_f32_16x16x16_bf16 %0, %1, %2, %0"
               : "+v"(d) : "v"(a), "v"(b));
  return d;
#endif
}

// XCD-aware chunked block swizzle (T1). HW assigns flat block f to XCD f%8;
// remap tile = (f&7)*cpx + (f>>3) so CONSECUTIVE tiles (which share a data
// panel) land on the SAME XCD's L2. Requires nwg % 8 == 0 (bijective).
__device__ __forceinline__ int xcd_swz(int f, int cpx) {
  return (f & 7) * cpx + (f >> 3);
}

// -------- prep: fp32->bf16 activations + transpose-convert all weights ------
// grid.x: [0,8192) cvt (4 f32/thread) | [8192,12288) 32x32 transpose tiles
__global__ void prep(const float* __restrict__ ref, u16* __restrict__ refb,
                     const float* __restrict__ tgt, u16* __restrict__ tgtb,
                     const float* __restrict__ Wq, u16* __restrict__ Wqt,
                     const float* __restrict__ Wkv, u16* __restrict__ Wkvt,
                     const float* __restrict__ Wp, u16* __restrict__ Wpt) {
  __shared__ float tile[32][33];
  int blk = blockIdx.x;
  int t = threadIdx.x;
  if (blk < 8192) {
    const float* in; u16* out;
    if (blk < 4096) { in = ref; out = refb; } else { in = tgt; out = tgtb; blk -= 4096; }
    int i = (blk * 256 + t) * 4;
    float4 f = *reinterpret_cast<const float4*>(in + i);
    ushort4 o;
    o.x = f2bf(f.x); o.y = f2bf(f.y); o.z = f2bf(f.z); o.w = f2bf(f.w);
    *reinterpret_cast<ushort4*>(out + i) = o;
    return;
  }
  blk -= 8192;                       // 0..4095: x = blk & 127, y = blk >> 7
  int x = blk & 127, by = blk >> 7;
  const float* in; u16* out; int N;
  if (x < 32)       { in = Wq;  out = Wqt;  N = CH;     }
  else if (x < 96)  { in = Wkv; out = Wkvt; N = 2 * CH; x -= 32; }
  else              { in = Wp;  out = Wpt;  N = CH;     x -= 96; }
  const int K = CH;
  int bn = x * 32, bk = by * 32;
  int tx = t & 31, ty = t >> 5;
  #pragma unroll
  for (int i = ty; i < 32; i += 8)
    tile[i][tx] = in[(size_t)(bk + i) * N + bn + tx];
  __syncthreads();
  #pragma unroll
  for (int i = ty; i < 32; i += 8)
    out[(size_t)(bn + i) * K + bk + tx] = f2bf(tile[tx][i]);
}

// ---------------- fused Q-proj + KV-proj GEMM, dbuf, 3 blocks/CU -------------
// bx < 16 : KV -> Karr (QK a-frag order) / Varr (PV b-frag order)
// bx >= 16: Q  -> q[B,H,M,hd] prescaled by hd^-0.5*log2(e)
// XCD swizzle: 24 consecutive flat blocks (one by-panel) -> same XCD L2.
__global__ __launch_bounds__(256, 3)
void gemm_qkv(const u16* __restrict__ tgtb, const u16* __restrict__ refb,
              const u16* __restrict__ Wqt, const u16* __restrict__ Wkvt,
              u16* __restrict__ qb, u16* __restrict__ karr, u16* __restrict__ varr)
{
  __shared__ __align__(16) u16 As[2][4096];
  __shared__ __align__(16) u16 Bs[2][4096];
  const int tid = threadIdx.x;
  const int lane = tid & 63, wave = tid >> 6;
  const int l16 = lane & 15, q = lane >> 4;
  const int tflat = xcd_swz(blockIdx.y * 24 + blockIdx.x, 96);  // 768 blocks
  const int bx = tflat % 24, by = tflat / 24;
  const bool isQ = bx >= 16;
  const u16* A  = isQ ? tgtb : refb;
  const u16* Bt = isQ ? Wqt : Wkvt;
  const int n0 = (isQ ? (bx - 16) : bx) * 128;
  const int m0 = by * 128;
  const int wm = (wave >> 1) * 64, wn = (wave & 1) * 64;
  const int Kdim = CH;
  const int c = tid, c2 = tid + 256;
  const int ar = c >> 2, ac = (c & 3) << 3, ar2 = c2 >> 2, ac2 = (c2 & 3) << 3;

  f4 acc[4][4] = {};

  #define STAGE_G(buf, k0)                                                      \
    { __builtin_amdgcn_global_load_lds(                                         \
          GAS(&A[(size_t)(m0 + ar) * Kdim + (k0) + ac]),                        \
          LAS(&As[buf][c << 3]), 16, 0, 0);                                     \
      __builtin_amdgcn_global_load_lds(                                         \
          GAS(&A[(size_t)(m0 + ar2) * Kdim + (k0) + ac2]),                      \
          LAS(&As[buf][c2 << 3]), 16, 0, 0);                                    \
      __builtin_amdgcn_global_load_lds(                                         \
          GAS(&Bt[(size_t)(n0 + ar) * Kdim + (k0) + ac]),                       \
          LAS(&Bs[buf][c << 3]), 16, 0, 0);                                     \
      __builtin_amdgcn_global_load_lds(                                         \
          GAS(&Bt[(size_t)(n0 + ar2) * Kdim + (k0) + ac2]),                     \
          LAS(&Bs[buf][c2 << 3]), 16, 0, 0); }

  STAGE_G(0, 0);
  for (int kk = 0; kk < 32; ++kk) {
    __syncthreads();
    if (kk < 31) STAGE_G((kk + 1) & 1, (kk + 1) * 32);
    const u16* as = As[kk & 1];
    const u16* bs = Bs[kk & 1];
    bf8 a[4], b[4];
    #pragma unroll
    for (int i = 0; i < 4; ++i)
      a[i] = *reinterpret_cast<const bf8*>(&as[(wm + i * 16 + l16) * 32 + q * 8]);
    #pragma unroll
    for (int j = 0; j < 4; ++j)
      b[j] = *reinterpret_cast<const bf8*>(&bs[(wn + j * 16 + l16) * 32 + q * 8]);
    #pragma unroll
    for (int i = 0; i < 4; ++i)
      #pragma unroll
      for (int j = 0; j < 4; ++j)
        acc[i][j] = MFMA32(a[i], b[j], acc[i][j]);
  }
  #undef STAGE_G

  // epilogue — C/D layout: col = lane&15, row = (lane>>4)*4 + reg   [m89/m91]
  #pragma unroll
  for (int i = 0; i < 4; ++i) {
    const int mbase = m0 + wm + i * 16 + q * 4;
    const int b = mbase >> 11, ns0 = mbase & (SEQ - 1);
    #pragma unroll
    for (int j = 0; j < 4; ++j) {
      const int n = n0 + wn + j * 16 + l16;
      if (isQ) {
        int h = n >> 6, d = n & 63;
        #pragma unroll
        for (int r = 0; r < 4; ++r)
          qb[(size_t)((b * NH + h) * SEQ + ns0 + r) * HD + d] =
              f2bf(acc[i][j][r] * 0.1803368801f);
      } else if (n < CH) {  // K -> a-frag order (scalar: r stride = 16B)
        int h = n >> 6, d = n & 63;
        size_t base = (size_t)(b * NH + h) * SEQ * HD;
        int off = (((ns0 >> 4) * 2 + (d >> 5)) * 4 + ((d >> 3) & 3)) * 128
                  + (d & 7);
        #pragma unroll
        for (int r = 0; r < 4; ++r)
          karr[base + off + ((ns0 + r) & 15) * 8] = f2bf(acc[i][j][r]);
      } else {  // V -> paired b-frag order (b128 loads in attn): 8B store
        int c2v = n - CH, h = c2v >> 6, d = c2v & 63;
        size_t base = (size_t)(b * NH + h) * SEQ * HD;
        int off = (((ns0 >> 4) * 2 + (d >> 5)) * 4 + ((ns0 >> 2) & 3)) * 128
                  + (d & 15) * 8 + ((d >> 4) & 1) * 4;
        ushort4 st;
        st.x = f2bf(acc[i][j][0]); st.y = f2bf(acc[i][j][1]);
        st.z = f2bf(acc[i][j][2]); st.w = f2bf(acc[i][j][3]);
        *reinterpret_cast<ushort4*>(&varr[base + off]) = st;
      }
    }
  }
}

// ------- out-proj GEMM: 64x128 tile, grid (8,64)=512 blocks -> 2/CU ---------
// XCD swizzle: 8 consecutive flat blocks (one A-panel) -> same XCD L2.
__global__ __launch_bounds__(256, 2)
void gemm_proj(const u16* __restrict__ A, const u16* __restrict__ Bt,
               float* __restrict__ fo, const float* __restrict__ bias)
{
  __shared__ __align__(16) u16 As[2][2048];   // 64 x 32
  __shared__ __align__(16) u16 Bs[2][4096];   // 128 x 32
  const int tid = threadIdx.x;
  const int lane = tid & 63, wave = tid >> 6;
  const int l16 = lane & 15, q = lane >> 4;
  const int tflat = xcd_swz(blockIdx.y * 8 + blockIdx.x, 64);   // 512 blocks
  const int m0 = (tflat / 8) * 64, n0 = (tflat % 8) * 128;
  const int wm = (wave >> 1) * 32, wn = (wave & 1) * 64;
  const int Kdim = CH;
  const int c = tid, c2 = tid + 256;
  const int ar = c >> 2, ac = (c & 3) << 3, ar2 = c2 >> 2, ac2 = (c2 & 3) << 3;

  f4 acc[2][4] = {};

  const int aar = c >> 2;            // 0..63
  const int aac = (c & 3) << 3;
  #define STAGE_P(buf, k0)                                                      \
    { __builtin_amdgcn_global_load_lds(                                         \
          GAS(&A[(size_t)(m0 + aar) * Kdim + (k0) + aac]),                      \
          LAS(&As[buf][c << 3]), 16, 0, 0);                                     \
      __builtin_amdgcn_global_load_lds(                                         \
          GAS(&Bt[(size_t)(n0 + ar) * Kdim + (k0) + ac]),                       \
          LAS(&Bs[buf][c << 3]), 16, 0, 0);                                     \
      __builtin_amdgcn_global_load_lds(                                         \
          GAS(&Bt[(size_t)(n0 + ar2) * Kdim + (k0) + ac2]),                     \
          LAS(&Bs[buf][c2 << 3]), 16, 0, 0); }

  STAGE_P(0, 0);
  for (int kk = 0; kk < 32; ++kk) {
    __syncthreads();
    if (kk < 31) STAGE_P((kk + 1) & 1, (kk + 1) * 32);
    const u16* as = As[kk & 1];
    const u16* bs = Bs[kk & 1];
    bf8 a[2], b[4];
    #pragma unroll
    for (int i = 0; i < 2; ++i)
      a[i] = *reinterpret_cast<const bf8*>(&as[(wm + i * 16 + l16) * 32 + q * 8]);
    #pragma unroll
    for (int j = 0; j < 4; ++j)
      b[j] = *reinterpret_cast<const bf8*>(&bs[(wn + j * 16 + l16) * 32 + q * 8]);
    #pragma unroll
    for (int i = 0; i < 2; ++i)
      #pragma unroll
      for (int j = 0; j < 4; ++j)
        acc[i][j] = MFMA32(a[i], b[j], acc[i][j]);
  }
  #undef STAGE_P

  #pragma unroll
  for (int i = 0; i < 2; ++i) {
    const int mbase = m0 + wm + i * 16 + q * 4;
    #pragma unroll
    for (int j = 0; j < 4; ++j) {
      const int n = n0 + wn + j * 16 + l16;
      #pragma unroll
      for (int r = 0; r < 4; ++r)
        fo[(size_t)(mbase + r) * CH + n] = acc[i][j][r] + bias[n];
    }
  }
}

// ------------- flash attention (transposed-S, fixed-max, NO split) ----------
// grid: (M/64, B*H), 256 threads (4 waves); wave owns 16 Q-rows. Full seq
// per block (KVBLK=64, 32 t-iters, LDS 32 KB). 1024 blocks -> 4/CU ->
// 16 waves/CU. Inner loop verbatim from round 11 (passed, 57.7 us).
// XCD swizzle: 32 consecutive flat blocks (one bh's K/V) -> same XCD L2.
__global__ __launch_bounds__(256, 4)
void attn(const u16* __restrict__ Q, const u16* __restrict__ Karr,
          const u16* __restrict__ Varr, u16* __restrict__ X)
{
  __shared__ __align__(16) u16 Ks[2][4096];   // 2 x 8 KB (64 x 64 tile)
  __shared__ __align__(16) u16 Vs[2][4096];   // 2 x 8 KB
  const int tid = threadIdx.x;
  const int lane = tid & 63;
  const int l16 = lane & 15, q = lane >> 4;
  const int tflat = xcd_swz(blockIdx.y * 32 + blockIdx.x, 128); // 1024 blocks
  const int bh = tflat / 32;
  const int m0 = (tflat % 32) * 64;
  const int wm = (tid >> 6) * 16;             // wave -> 16 Q-rows

  const u16* Qb = Q    + (size_t)bh * SEQ * HD;
  const u16* Kb = Karr + (size_t)bh * SEQ * HD;
  const u16* Vb = Varr + (size_t)bh * SEQ * HD;

  // Q fragments (b-operand layout [n=l16][k=q*8+j]), resident all kernel
  bf8 qf[2];
  #pragma unroll
  for (int s = 0; s < 2; ++s)
    qf[s] = *reinterpret_cast<const bf8*>(
        &Qb[(size_t)(m0 + wm + l16) * HD + s * 32 + q * 8]);

  const short one_bf = 0x3F80;               // bf16(1.0)
  const bf4 ones = {one_bf, one_bf, one_bf, one_bf};

  f4 o[4] = {};     // O frag: row m=q*4+r, col d=dt*16+l16
  f4 ds = {};       // denominator frag: ds[r] = rowsum for m=q*4+r

  // staging: tile = 64 rows x 64 dims = 4096 u16 per array; 256 thr x 16 elems
  #define STAGE_A(buf, t)                                                      \
    { __builtin_amdgcn_global_load_lds(GAS(Kb + (size_t)(t) * 4096 + tid * 8), \
                                       LAS(&Ks[buf][tid * 8]), 16, 0, 0);      \
      __builtin_amdgcn_global_load_lds(GAS(Kb + (size_t)(t) * 4096 + 2048 + tid * 8), \
                                       LAS(&Ks[buf][2048 + tid * 8]), 16, 0, 0); \
      __builtin_amdgcn_global_load_lds(GAS(Vb + (size_t)(t) * 4096 + tid * 8), \
                                       LAS(&Vs[buf][tid * 8]), 16, 0, 0);      \
      __builtin_amdgcn_global_load_lds(GAS(Vb + (size_t)(t) * 4096 + 2048 + tid * 8), \
                                       LAS(&Vs[buf][2048 + tid * 8]), 16, 0, 0); }

  STAGE_A(0, 0);
  for (int t = 0; t < 32; ++t) {
    __syncthreads();
    if (t < 31) STAGE_A((t + 1) & 1, t + 1);
    const u16* ks = Ks[t & 1];
    const u16* vs = Vs[t & 1];

    // S^T tiles + exp + pack, all in registers (4 x 16 k-rows per step)
    bf4 pa[4];
    #pragma unroll
    for (int j = 0; j < 4; ++j) {
      bf8 kf0 = *reinterpret_cast<const bf8*>(&ks[((j * 2 + 0) * 4 + q) * 128 + l16 * 8]);
      bf8 kf1 = *reinterpret_cast<const bf8*>(&ks[((j * 2 + 1) * 4 + q) * 128 + l16 * 8]);
      f4 zf = {};
      zf = MFMA32(kf0, qf[0], zf);
      zf = MFMA32(kf1, qf[1], zf);
      union { bf4 v; uint32_t u[2]; } w;
      w.u[0] = pk2bf(fexp2(zf[0]), fexp2(zf[1]));
      w.u[1] = pk2bf(fexp2(zf[2]), fexp2(zf[3]));
      pa[j] = w.v;
    }

    // O += P * V ; denominator += P * ones; V frags as b128 pairs
    #pragma unroll
    for (int j = 0; j < 4; ++j) {
      ds = MFMA16(pa[j], ones, ds);
      #pragma unroll
      for (int dh = 0; dh < 2; ++dh) {
        bf8 vv = *reinterpret_cast<const bf8*>(&vs[((j * 2 + dh) * 4 + q) * 128 + l16 * 8]);
        bf4 v0 = __builtin_shufflevector(vv, vv, 0, 1, 2, 3);
        bf4 v1 = __builtin_shufflevector(vv, vv, 4, 5, 6, 7);
        o[dh * 2 + 0] = MFMA16(pa[j], v0, o[dh * 2 + 0]);
        o[dh * 2 + 1] = MFMA16(pa[j], v1, o[dh * 2 + 1]);
      }
    }
  }
  #undef STAGE_A

  // normalize + write x[b, m, h*64+d] (bf16) directly
  const int b = bh >> 4, h = bh & (NH - 1);
  #pragma unroll
  for (int r = 0; r < 4; ++r) {
    float ir = 1.0f / ds[r];
    int m = m0 + wm + q * 4 + r;
    #pragma unroll
    for (int dt = 0; dt < 4; ++dt) {
      int d = dt * 16 + l16;
      X[(size_t)(b * SEQ + m) * CH + h * HD + d] = f2bf(o[dt][r] * ir);
    }
  }
}

// ---------------- launch ----------------
extern "C" void kernel_launch(void* const* d_in, const int* in_sizes, int n_in,
                              void* d_out, int out_size, void* d_ws, size_t ws_size,
                              hipStream_t stream) {
  const float* ref   = (const float*)d_in[0];   // [B,N,C]
  const float* tgt   = (const float*)d_in[1];   // [B,M,C]
  const float* Wq    = (const float*)d_in[2];   // [C,C]
  const float* Wkv   = (const float*)d_in[3];   // [C,2C]
  const float* Wproj = (const float*)d_in[4];   // [C,C]
  const float* bproj = (const float*)d_in[5];   // [C]
  float* out = (float*)d_out;                   // [B,M,C] fp32

  // workspace layout (bytes): total 56 MiB
  char* ws = (char*)d_ws;
  u16* refb = (u16*)(ws);                 // 8 MiB
  u16* tgtb = (u16*)(ws + (8  << 20));    // 8 MiB
  u16* Wqt  = (u16*)(ws + (16 << 20));    // 2 MiB  [C,C]^T
  u16* Wkvt = (u16*)(ws + (18 << 20));    // 4 MiB  [2C,C]^T
  u16* Wpt  = (u16*)(ws + (22 << 20));    // 2 MiB
  u16* qb   = (u16*)(ws + (24 << 20));    // 8 MiB  [B,H,M,hd] (pre-scaled)
  u16* karr = (u16*)(ws + (32 << 20));    // 8 MiB  a-frag order
  u16* varr = (u16*)(ws + (40 << 20));    // 8 MiB  paired b-frag order
  u16* xb   = (u16*)(ws + (48 << 20));    // 8 MiB  [B*M, C]

  prep<<<12288, 256, 0, stream>>>(ref, refb, tgt, tgtb, Wq, Wqt, Wkv, Wkvt, Wproj, Wpt);

  gemm_qkv<<<dim3(24, 32), 256, 0, stream>>>(tgtb, refb, Wqt, Wkvt, qb, karr, varr);

  attn<<<dim3(32, 32), 256, 0, stream>>>(qb, karr, varr, xb);

  gemm_proj<<<dim3(8, 64), 256, 0, stream>>>(xb, Wpt, out, bproj);
}